// Round 13
// baseline (196.603 us; speedup 1.0000x reference)
//
#include <hip/hip_runtime.h>

#define F_IN 128
#define F_OUT 64
#define GROWS 128        // rows per gemm block (2 rows/thread at 1024 thr)
#define XSTRIDE 33       // float4 per x_lds row (132 floats, 16B aligned, padded)

#define NPB 128          // nodes per bucket
#define NPB_SHIFT 7
#define BCAP 800         // max buckets (nb = 782)
#define ECAP 2560        // edges per baccum chunk (= 5 records/thread at 512 thr)
#define TILE 8192        // edges per tile in multisplit
#define BSTH 1024        // fused-kernel threads
#define TMAX 256         // max tiles (T = ceil(E/TILE) = 196)

// fp32 -> bf16 round-to-nearest-even.
__device__ inline unsigned short f2bf(float f) {
    const unsigned u = __float_as_uint(f);
    return (unsigned short)((u + 0x7FFFu + ((u >> 16) & 1u)) >> 16);
}

// Shared-memory union: gemm role vs multisplit role (whole-block roles).
struct GemmSh {
    float4 w[F_IN * F_OUT / 4];              // 32 KB
    float4 xt[GROWS * XSTRIDE];              // 67.6 KB
};
struct ScatSh {
    int2 ebuf2[TILE];                        // 64 KB (rank-permuted records)
    int  h[BCAP];                            // 3.2 KB
    int  lcur[BCAP];                         // 3.2 KB
    int  wsum[16];
    int  woff[16];
};
union FusedSh { GemmSh g; ScatSh s; };       // ~100 KB -> 1 block/CU

// ---------------------------------------------------------------------------
// Fused kernel: blocks [0,T) = tile-private edge multisplit; blocks [T,T+G) =
// support(bf16) = x @ weight. gemm inner loop reads x as float4 (k-groups of
// 4): 6 b128 LDS instr per 4 k's for 32 FMAs -> FMA-bound, not LDS-bound.
// ---------------------------------------------------------------------------
__global__ __launch_bounds__(BSTH) void fused_kernel(const float* __restrict__ x,
                                                     const float* __restrict__ w,
                                                     unsigned short* __restrict__ support,
                                                     int n_nodes,
                                                     const float* __restrict__ edge_val,
                                                     const int* __restrict__ edge_src,
                                                     const int* __restrict__ edge_dst,
                                                     int* __restrict__ toff,
                                                     int2* __restrict__ sorted,
                                                     int n_edges, int nb, int T) {
    __shared__ FusedSh u;
    const int tid = threadIdx.x;

    if ((int)blockIdx.x >= T) {
        // ================= gemm role =================
        const int row0 = (blockIdx.x - T) * GROWS;

        {   // stage weight: 2048 f4, 2 per thread
            const float4* w4 = (const float4*)w;
            #pragma unroll
            for (int i = tid; i < F_IN * F_OUT / 4; i += BSTH) u.g.w[i] = w4[i];
        }
        {   // stage x tile: 128 rows x 32 f4, 4 per thread
            const float4* x4 = (const float4*)x;
            #pragma unroll
            for (int i = tid; i < GROWS * (F_IN / 4); i += BSTH) {
                const int r  = i >> 5;
                const int k4 = i & 31;
                const int row = row0 + r;
                float4 v = make_float4(0.f, 0.f, 0.f, 0.f);
                if (row < n_nodes) v = x4[(size_t)row * (F_IN / 4) + k4];
                u.g.xt[r * XSTRIDE + k4] = v;
            }
        }
        __syncthreads();

        const int tf = tid & 15;     // feats 4tf..4tf+3
        const int tr = tid >> 4;     // rows tr and tr+64

        float acc[2][4] = {};
        #pragma unroll 4
        for (int k4 = 0; k4 < F_IN / 4; ++k4) {
            const float4 xA = u.g.xt[tr * XSTRIDE + k4];          // 4 addrs/wave
            const float4 xB = u.g.xt[(tr + 64) * XSTRIDE + k4];
            const float4 w0 = u.g.w[(4 * k4 + 0) * 16 + tf];      // 16 addrs, 2-way
            const float4 w1 = u.g.w[(4 * k4 + 1) * 16 + tf];
            const float4 w2 = u.g.w[(4 * k4 + 2) * 16 + tf];
            const float4 w3 = u.g.w[(4 * k4 + 3) * 16 + tf];
            acc[0][0] += xA.x * w0.x + xA.y * w1.x + xA.z * w2.x + xA.w * w3.x;
            acc[0][1] += xA.x * w0.y + xA.y * w1.y + xA.z * w2.y + xA.w * w3.y;
            acc[0][2] += xA.x * w0.z + xA.y * w1.z + xA.z * w2.z + xA.w * w3.z;
            acc[0][3] += xA.x * w0.w + xA.y * w1.w + xA.z * w2.w + xA.w * w3.w;
            acc[1][0] += xB.x * w0.x + xB.y * w1.x + xB.z * w2.x + xB.w * w3.x;
            acc[1][1] += xB.x * w0.y + xB.y * w1.y + xB.z * w2.y + xB.w * w3.y;
            acc[1][2] += xB.x * w0.z + xB.y * w1.z + xB.z * w2.z + xB.w * w3.z;
            acc[1][3] += xB.x * w0.w + xB.y * w1.w + xB.z * w2.w + xB.w * w3.w;
        }
        #pragma unroll
        for (int i = 0; i < 2; ++i) {
            const int row = row0 + tr + 64 * i;
            if (row < n_nodes) {
                ushort4 o;
                o.x = f2bf(acc[i][0]); o.y = f2bf(acc[i][1]);
                o.z = f2bf(acc[i][2]); o.w = f2bf(acc[i][3]);
                *(ushort4*)&support[(size_t)row * F_OUT + 4 * tf] = o;
            }
        }
        return;
    }

    // ================= multisplit role =================
    const int te  = blockIdx.x * TILE;
    const int cnt = min(TILE, n_edges - te);

    for (int i = tid; i < BCAP; i += BSTH) u.s.h[i] = 0;
    __syncthreads();

    // Pass A: load edges into REGISTERS (2 int4-tiles/thread) + LDS hist.
    const int cnt4 = cnt >> 2;
    const int4*   s4 = (const int4*)(edge_src + te);
    const int4*   d4 = (const int4*)(edge_dst + te);
    const float4* v4 = (const float4*)(edge_val + te);
    int4 rs[2], rd[2]; float4 rv[2];
    #pragma unroll
    for (int it = 0; it < 2; ++it) {
        const int t = tid + it * BSTH;
        if (t < cnt4) {
            rs[it] = s4[t]; rd[it] = d4[t]; rv[it] = v4[t];
            atomicAdd(&u.s.h[rd[it].x >> NPB_SHIFT], 1);
            atomicAdd(&u.s.h[rd[it].y >> NPB_SHIFT], 1);
            atomicAdd(&u.s.h[rd[it].z >> NPB_SHIFT], 1);
            atomicAdd(&u.s.h[rd[it].w >> NPB_SHIFT], 1);
        }
    }
    if (tid == 0) {   // tail (<=3 edges): hist only, ranked in pass B
        for (int e = cnt4 << 2; e < cnt; ++e)
            atomicAdd(&u.s.h[edge_dst[te + e] >> NPB_SHIFT], 1);
    }
    __syncthreads();

    // Shuffle-based block scan of bucket counts (16 waves).
    const int v = (tid < nb) ? u.s.h[tid] : 0;
    int s = v;
    #pragma unroll
    for (int off = 1; off < 64; off <<= 1) {
        const int t = __shfl_up(s, off, 64);
        if ((tid & 63) >= off) s += t;
    }
    const int wave = tid >> 6;
    if ((tid & 63) == 63) u.s.wsum[wave] = s;
    __syncthreads();
    if (tid < 16) {
        const int ws = u.s.wsum[tid];
        int sc = ws;
        #pragma unroll
        for (int off = 1; off < 16; off <<= 1) {
            const int t = __shfl_up(sc, off, 64);
            if (tid >= off) sc += t;
        }
        u.s.woff[tid] = sc - ws;   // exclusive wave offset
    }
    __syncthreads();

    int* trow = toff + (size_t)blockIdx.x * (nb + 1);
    if (tid < nb) {
        const int start = s + u.s.woff[wave] - v;   // exclusive start
        u.s.lcur[tid] = start;
        trow[tid] = start;
    }
    if (tid == 0) trow[nb] = cnt;
    __syncthreads();

    // Pass B: rank (LDS cursor) and write records DIRECTLY permuted into LDS.
    #pragma unroll
    for (int it = 0; it < 2; ++it) {
        const int t = tid + it * BSTH;
        if (t < cnt4) {
            int b, r;
            b = rd[it].x >> NPB_SHIFT; r = atomicAdd(&u.s.lcur[b], 1);
            u.s.ebuf2[r] = make_int2(rs[it].x | ((rd[it].x & (NPB - 1)) << 20), __float_as_int(rv[it].x));
            b = rd[it].y >> NPB_SHIFT; r = atomicAdd(&u.s.lcur[b], 1);
            u.s.ebuf2[r] = make_int2(rs[it].y | ((rd[it].y & (NPB - 1)) << 20), __float_as_int(rv[it].y));
            b = rd[it].z >> NPB_SHIFT; r = atomicAdd(&u.s.lcur[b], 1);
            u.s.ebuf2[r] = make_int2(rs[it].z | ((rd[it].z & (NPB - 1)) << 20), __float_as_int(rv[it].z));
            b = rd[it].w >> NPB_SHIFT; r = atomicAdd(&u.s.lcur[b], 1);
            u.s.ebuf2[r] = make_int2(rs[it].w | ((rd[it].w & (NPB - 1)) << 20), __float_as_int(rv[it].w));
        }
    }
    if (tid == 0) {   // tail
        for (int e = cnt4 << 2; e < cnt; ++e) {
            const int dd = edge_dst[te + e];
            const int b = dd >> NPB_SHIFT;
            const int r = atomicAdd(&u.s.lcur[b], 1);
            u.s.ebuf2[r] = make_int2(edge_src[te + e] | ((dd & (NPB - 1)) << 20),
                                     __float_as_int(edge_val[te + e]));
        }
    }
    __syncthreads();

    // Pass C: stream the sorted tile to its private region (coalesced).
    for (int k = tid; k < cnt; k += BSTH)
        sorted[(size_t)te + k] = u.s.ebuf2[k];
}

// ---------------------------------------------------------------------------
// baccum v6: register staging (5 records/thread, statically unrolled — no
// ebuf LDS array, one fewer LDS pass; LDS ~23 KB). uint4 8-lane gather
// (16 B/lane, 8 edges per wave-instruction), register acc, fused ReLU.
// ---------------------------------------------------------------------------
__global__ __launch_bounds__(512) void baccum_kernel(const unsigned short* __restrict__ support,
                                                     const int2* __restrict__ sorted,
                                                     const int* __restrict__ toff,
                                                     float* __restrict__ out,
                                                     int n_nodes, int T, int nb) {
    __shared__ int2 ebuf2[ECAP];                   // 20 KB (rank-permuted)
    __shared__ int tstart[TMAX];
    __shared__ int toffb[TMAX];
    __shared__ int wsum3[4];
    __shared__ int total_s;
    __shared__ int hist[NPB];
    __shared__ int node_off[NPB + 1];
    __shared__ int cursor[NPB];
    __shared__ int wsum2[2];

    const int tid = threadIdx.x;
    const int b = blockIdx.x;

    int mycnt = 0, myoff = 0;
    if (tid < TMAX) {
        if (tid < T) {
            const int s0 = toff[(size_t)tid * (nb + 1) + b];
            const int e0 = toff[(size_t)tid * (nb + 1) + b + 1];
            toffb[tid] = s0;
            mycnt = e0 - s0;
        }
        int s = mycnt;
        #pragma unroll
        for (int off = 1; off < 64; off <<= 1) {
            const int t = __shfl_up(s, off, 64);
            if ((tid & 63) >= off) s += t;
        }
        if ((tid & 63) == 63) wsum3[tid >> 6] = s;
        myoff = s - mycnt;
    }
    __syncthreads();
    if (tid < TMAX && tid < T) {
        int add = 0;
        const int wv = tid >> 6;
        for (int q2 = 0; q2 < wv; ++q2) add += wsum3[q2];
        tstart[tid] = myoff + add;
    }
    if (tid == 0) total_s = wsum3[0] + wsum3[1] + wsum3[2] + wsum3[3];
    __syncthreads();
    const int total = total_s;

    const int g8 = tid >> 3;        // group 0..63 (owns nodes g8, g8+64)
    const int q  = tid & 7;         // uint4 slot: feats 8q..8q+7
    const uint4* sup = (const uint4*)support;   // row = 8 uint4 = 128 B

    float4 accA[2], accB[2];        // node j: feats 8q..8q+3 / 8q+4..8q+7
    #pragma unroll
    for (int j = 0; j < 2; ++j) {
        accA[j] = make_float4(0.f, 0.f, 0.f, 0.f);
        accB[j] = make_float4(0.f, 0.f, 0.f, 0.f);
    }

    for (int cb = 0; cb < total; cb += ECAP) {
        const int cnt = min(ECAP, total - cb);

        __syncthreads();                // gather of prev chunk done
        if (tid < NPB) hist[tid] = 0;
        __syncthreads();

        // Pass 1: fetch records into REGISTERS (static 5-slot unroll) + hist.
        int2 rec[5];
        #pragma unroll
        for (int it = 0; it < 5; ++it) {
            const int i = tid + it * 512;
            if (i < cnt) {
                const int g = cb + i;
                int lo = 0, hi = T - 1;
                while (lo < hi) {                  // max t with tstart[t] <= g
                    const int mid = (lo + hi + 1) >> 1;
                    if (tstart[mid] <= g) lo = mid; else hi = mid - 1;
                }
                const int2 ev = sorted[(size_t)lo * TILE + toffb[lo] + (g - tstart[lo])];
                rec[it] = ev;
                atomicAdd(&hist[((unsigned)ev.x) >> 20], 1);
            }
        }
        __syncthreads();

        // Shuffle scan of 128 node bins (2 waves).
        {
            int v = 0;
            if (tid < NPB) v = hist[tid];
            int s = v;
            if (tid < NPB) {
                #pragma unroll
                for (int off = 1; off < 64; off <<= 1) {
                    const int t = __shfl_up(s, off, 64);
                    if ((tid & 63) >= off) s += t;
                }
                if ((tid & 63) == 63) wsum2[tid >> 6] = s;
            }
            __syncthreads();
            if (tid < NPB) {
                const int incl = s + ((tid >= 64) ? wsum2[0] : 0);
                node_off[tid + 1] = incl;
                cursor[tid] = incl - v;
                if (tid == 0) node_off[0] = 0;
            }
        }
        __syncthreads();

        // Pass 2: rank from registers, write permuted into ebuf2.
        #pragma unroll
        for (int it = 0; it < 5; ++it) {
            const int i = tid + it * 512;
            if (i < cnt) {
                const int2 ev = rec[it];
                const int r = atomicAdd(&cursor[((unsigned)ev.x) >> 20], 1);
                ebuf2[r] = ev;
            }
        }
        __syncthreads();

        // Register gather, 8-wide independent uint4 batches.
        #pragma unroll
        for (int j = 0; j < 2; ++j) {
            const int nl = g8 + 64 * j;
            int k = node_off[nl];
            const int ke = node_off[nl + 1];
            float4 aA = accA[j], aB = accB[j];
            while (k + 8 <= ke) {
                int2 e[8];
                uint4 s[8];
                #pragma unroll
                for (int u2 = 0; u2 < 8; ++u2) e[u2] = ebuf2[k + u2];      // broadcast
                #pragma unroll
                for (int u2 = 0; u2 < 8; ++u2)
                    s[u2] = sup[(size_t)(e[u2].x & 0xFFFFF) * 8 + q];      // independent
                #pragma unroll
                for (int u2 = 0; u2 < 8; ++u2) {
                    const float v = __int_as_float(e[u2].y);
                    aA.x += v * __uint_as_float(s[u2].x << 16);
                    aA.y += v * __uint_as_float(s[u2].x & 0xFFFF0000u);
                    aA.z += v * __uint_as_float(s[u2].y << 16);
                    aA.w += v * __uint_as_float(s[u2].y & 0xFFFF0000u);
                    aB.x += v * __uint_as_float(s[u2].z << 16);
                    aB.y += v * __uint_as_float(s[u2].z & 0xFFFF0000u);
                    aB.z += v * __uint_as_float(s[u2].w << 16);
                    aB.w += v * __uint_as_float(s[u2].w & 0xFFFF0000u);
                }
                k += 8;
            }
            for (; k < ke; ++k) {
                const int2 e0 = ebuf2[k];
                const uint4 s0 = sup[(size_t)(e0.x & 0xFFFFF) * 8 + q];
                const float v0 = __int_as_float(e0.y);
                aA.x += v0 * __uint_as_float(s0.x << 16);
                aA.y += v0 * __uint_as_float(s0.x & 0xFFFF0000u);
                aA.z += v0 * __uint_as_float(s0.y << 16);
                aA.w += v0 * __uint_as_float(s0.y & 0xFFFF0000u);
                aB.x += v0 * __uint_as_float(s0.z << 16);
                aB.y += v0 * __uint_as_float(s0.z & 0xFFFF0000u);
                aB.z += v0 * __uint_as_float(s0.w << 16);
                aB.w += v0 * __uint_as_float(s0.w & 0xFFFF0000u);
            }
            accA[j] = aA; accB[j] = aB;
        }
    }

    // Writeout (empty buckets write zeros; ReLU(0)=0 matches segment_sum).
    const int base = b << NPB_SHIFT;
    #pragma unroll
    for (int j = 0; j < 2; ++j) {
        const int node = base + g8 + 64 * j;
        if (node < n_nodes) {
            float4 vA = accA[j], vB = accB[j];
            vA.x = fmaxf(vA.x, 0.f); vA.y = fmaxf(vA.y, 0.f);
            vA.z = fmaxf(vA.z, 0.f); vA.w = fmaxf(vA.w, 0.f);
            vB.x = fmaxf(vB.x, 0.f); vB.y = fmaxf(vB.y, 0.f);
            vB.z = fmaxf(vB.z, 0.f); vB.w = fmaxf(vB.w, 0.f);
            ((float4*)out)[(size_t)node * 16 + 2 * q + 0] = vA;
            ((float4*)out)[(size_t)node * 16 + 2 * q + 1] = vB;
        }
    }
}

// ---------------------------------------------------------------------------
// Fallback: atomic path with bf16 support.
// ---------------------------------------------------------------------------
__global__ __launch_bounds__(256) void scatter_kernel(const unsigned short* __restrict__ support,
                                                      const float* __restrict__ edge_val,
                                                      const int* __restrict__ edge_src,
                                                      const int* __restrict__ edge_dst,
                                                      float* __restrict__ out,
                                                      int n_edges) {
    const long gid = (long)blockIdx.x * blockDim.x + threadIdx.x;
    const int e = (int)(gid >> 4);
    if (e >= n_edges) return;
    const int q = (int)(gid & 15);
    const int src   = edge_src[e];
    const int dst   = edge_dst[e];
    const float val = edge_val[e];
    const uint2 s = ((const uint2*)support)[(size_t)src * 16 + q];
    float* o = &out[(size_t)dst * F_OUT + q * 4];
    atomicAdd(o + 0, val * __uint_as_float(s.x << 16));
    atomicAdd(o + 1, val * __uint_as_float(s.x & 0xFFFF0000u));
    atomicAdd(o + 2, val * __uint_as_float(s.y << 16));
    atomicAdd(o + 3, val * __uint_as_float(s.y & 0xFFFF0000u));
}

__global__ __launch_bounds__(256) void relu_kernel(float* __restrict__ out, int n4) {
    const int i = blockIdx.x * blockDim.x + threadIdx.x;
    if (i < n4) {
        float4 v = ((float4*)out)[i];
        v.x = fmaxf(v.x, 0.f); v.y = fmaxf(v.y, 0.f);
        v.z = fmaxf(v.z, 0.f); v.w = fmaxf(v.w, 0.f);
        ((float4*)out)[i] = v;
    }
}

extern "C" void kernel_launch(void* const* d_in, const int* in_sizes, int n_in,
                              void* d_out, int out_size, void* d_ws, size_t ws_size,
                              hipStream_t stream) {
    const float* x        = (const float*)d_in[0];
    const float* w        = (const float*)d_in[1];
    const float* edge_val = (const float*)d_in[2];
    const int*   edge_src = (const int*)d_in[3];
    const int*   edge_dst = (const int*)d_in[4];
    float* out = (float*)d_out;

    const int n_nodes = in_sizes[0] / F_IN;   // 100000
    const int n_edges = in_sizes[2];          // 1600000
    const int nb = (n_nodes + NPB - 1) >> NPB_SHIFT;   // 782 buckets
    const int T  = (n_edges + TILE - 1) / TILE;        // 196 tiles
    const int G  = (n_nodes + GROWS - 1) / GROWS;      // 782 gemm blocks

    // Workspace: support bf16 (12.8 MB) | sorted (12.85 MB) | toff (0.61 MB)
    char* p = (char*)d_ws;
    unsigned short* support = (unsigned short*)p;
    p += (size_t)n_nodes * F_OUT * sizeof(unsigned short);
    p = (char*)(((size_t)p + 15) & ~(size_t)15);
    int2* sorted = (int2*)p;  p += (size_t)T * TILE * sizeof(int2);
    int*  toff   = (int*)p;   p += (size_t)T * (nb + 1) * sizeof(int);
    const size_t ws_needed = (size_t)(p - (char*)d_ws);

    const bool ok = (ws_size >= ws_needed) && (nb <= BCAP) && (n_nodes < (1 << 20))
                    && (T <= TMAX);
    if (ok) {
        fused_kernel<<<T + G, BSTH, 0, stream>>>(x, w, support, n_nodes,
                                                 edge_val, edge_src, edge_dst,
                                                 toff, sorted, n_edges, nb, T);
        baccum_kernel<<<nb, 512, 0, stream>>>(support, sorted, toff, out,
                                              n_nodes, T, nb);
    } else {
        // gemm only (T=0 -> all blocks take the gemm role)
        fused_kernel<<<G, BSTH, 0, stream>>>(x, w, support, n_nodes,
                                             edge_val, edge_src, edge_dst,
                                             nullptr, nullptr, n_edges, nb, 0);
        hipMemsetAsync(d_out, 0, (size_t)out_size * sizeof(float), stream);
        const long st = (long)n_edges * 16;
        scatter_kernel<<<(int)((st + 255) / 256), 256, 0, stream>>>(
            support, edge_val, edge_src, edge_dst, out, n_edges);
        const int n4o = out_size / 4;
        relu_kernel<<<(n4o + 255) / 256, 256, 0, stream>>>(out, n4o);
    }
}

// Round 14
// 176.529 us; speedup vs baseline: 1.1137x; 1.1137x over previous
//
#include <hip/hip_runtime.h>

#define F_IN 128
#define F_OUT 64
#define GROWS 128        // rows per gemm block (2 rows/thread at 1024 thr)
#define XSTRIDE 33       // float4 per x_lds row (132 floats, 16B aligned, padded)

#define NPB 128          // nodes per bucket
#define NPB_SHIFT 7
#define BCAP 800         // max buckets (nb = 782)
#define ECAP 2560        // edges staged per LDS chunk in baccum
#define TILE 8192        // edges per tile in multisplit
#define BSTH 1024        // fused-kernel threads
#define TMAX 256         // max tiles (T = ceil(E/TILE) = 196)

// fp32 -> bf16 round-to-nearest-even.
__device__ inline unsigned short f2bf(float f) {
    const unsigned u = __float_as_uint(f);
    return (unsigned short)((u + 0x7FFFu + ((u >> 16) & 1u)) >> 16);
}

// Shared-memory union: gemm role vs multisplit role (whole-block roles).
struct GemmSh {
    float4 w[F_IN * F_OUT / 4];              // 32 KB
    float4 xt[GROWS * XSTRIDE];              // 67.6 KB
};
struct ScatSh {
    int2 ebuf2[TILE];                        // 64 KB (rank-permuted records)
    int  h[BCAP];                            // 3.2 KB
    int  lcur[BCAP];                         // 3.2 KB
    int  wsum[16];
    int  woff[16];
};
union FusedSh { GemmSh g; ScatSh s; };       // ~100 KB -> 1 block/CU

// ---------------------------------------------------------------------------
// Fused kernel (round-13): blocks [0,T) = tile-private edge multisplit;
// blocks [T,T+G) = support(bf16) = x @ weight with float4 x reads.
// ---------------------------------------------------------------------------
__global__ __launch_bounds__(BSTH) void fused_kernel(const float* __restrict__ x,
                                                     const float* __restrict__ w,
                                                     unsigned short* __restrict__ support,
                                                     int n_nodes,
                                                     const float* __restrict__ edge_val,
                                                     const int* __restrict__ edge_src,
                                                     const int* __restrict__ edge_dst,
                                                     int* __restrict__ toff,
                                                     int2* __restrict__ sorted,
                                                     int n_edges, int nb, int T) {
    __shared__ FusedSh u;
    const int tid = threadIdx.x;

    if ((int)blockIdx.x >= T) {
        // ================= gemm role =================
        const int row0 = (blockIdx.x - T) * GROWS;

        {   // stage weight: 2048 f4, 2 per thread
            const float4* w4 = (const float4*)w;
            #pragma unroll
            for (int i = tid; i < F_IN * F_OUT / 4; i += BSTH) u.g.w[i] = w4[i];
        }
        {   // stage x tile: 128 rows x 32 f4, 4 per thread
            const float4* x4 = (const float4*)x;
            #pragma unroll
            for (int i = tid; i < GROWS * (F_IN / 4); i += BSTH) {
                const int r  = i >> 5;
                const int k4 = i & 31;
                const int row = row0 + r;
                float4 v = make_float4(0.f, 0.f, 0.f, 0.f);
                if (row < n_nodes) v = x4[(size_t)row * (F_IN / 4) + k4];
                u.g.xt[r * XSTRIDE + k4] = v;
            }
        }
        __syncthreads();

        const int tf = tid & 15;     // feats 4tf..4tf+3
        const int tr = tid >> 4;     // rows tr and tr+64

        float acc[2][4] = {};
        #pragma unroll 4
        for (int k4 = 0; k4 < F_IN / 4; ++k4) {
            const float4 xA = u.g.xt[tr * XSTRIDE + k4];
            const float4 xB = u.g.xt[(tr + 64) * XSTRIDE + k4];
            const float4 w0 = u.g.w[(4 * k4 + 0) * 16 + tf];
            const float4 w1 = u.g.w[(4 * k4 + 1) * 16 + tf];
            const float4 w2 = u.g.w[(4 * k4 + 2) * 16 + tf];
            const float4 w3 = u.g.w[(4 * k4 + 3) * 16 + tf];
            acc[0][0] += xA.x * w0.x + xA.y * w1.x + xA.z * w2.x + xA.w * w3.x;
            acc[0][1] += xA.x * w0.y + xA.y * w1.y + xA.z * w2.y + xA.w * w3.y;
            acc[0][2] += xA.x * w0.z + xA.y * w1.z + xA.z * w2.z + xA.w * w3.z;
            acc[0][3] += xA.x * w0.w + xA.y * w1.w + xA.z * w2.w + xA.w * w3.w;
            acc[1][0] += xB.x * w0.x + xB.y * w1.x + xB.z * w2.x + xB.w * w3.x;
            acc[1][1] += xB.x * w0.y + xB.y * w1.y + xB.z * w2.y + xB.w * w3.y;
            acc[1][2] += xB.x * w0.z + xB.y * w1.z + xB.z * w2.z + xB.w * w3.z;
            acc[1][3] += xB.x * w0.w + xB.y * w1.w + xB.z * w2.w + xB.w * w3.w;
        }
        #pragma unroll
        for (int i = 0; i < 2; ++i) {
            const int row = row0 + tr + 64 * i;
            if (row < n_nodes) {
                ushort4 o;
                o.x = f2bf(acc[i][0]); o.y = f2bf(acc[i][1]);
                o.z = f2bf(acc[i][2]); o.w = f2bf(acc[i][3]);
                *(ushort4*)&support[(size_t)row * F_OUT + 4 * tf] = o;
            }
        }
        return;
    }

    // ================= multisplit role =================
    const int te  = blockIdx.x * TILE;
    const int cnt = min(TILE, n_edges - te);

    for (int i = tid; i < BCAP; i += BSTH) u.s.h[i] = 0;
    __syncthreads();

    // Pass A: load edges into REGISTERS (2 int4-tiles/thread) + LDS hist.
    const int cnt4 = cnt >> 2;
    const int4*   s4 = (const int4*)(edge_src + te);
    const int4*   d4 = (const int4*)(edge_dst + te);
    const float4* v4 = (const float4*)(edge_val + te);
    int4 rs[2], rd[2]; float4 rv[2];
    #pragma unroll
    for (int it = 0; it < 2; ++it) {
        const int t = tid + it * BSTH;
        if (t < cnt4) {
            rs[it] = s4[t]; rd[it] = d4[t]; rv[it] = v4[t];
            atomicAdd(&u.s.h[rd[it].x >> NPB_SHIFT], 1);
            atomicAdd(&u.s.h[rd[it].y >> NPB_SHIFT], 1);
            atomicAdd(&u.s.h[rd[it].z >> NPB_SHIFT], 1);
            atomicAdd(&u.s.h[rd[it].w >> NPB_SHIFT], 1);
        }
    }
    if (tid == 0) {   // tail (<=3 edges): hist only, ranked in pass B
        for (int e = cnt4 << 2; e < cnt; ++e)
            atomicAdd(&u.s.h[edge_dst[te + e] >> NPB_SHIFT], 1);
    }
    __syncthreads();

    // Shuffle-based block scan of bucket counts (16 waves).
    const int v = (tid < nb) ? u.s.h[tid] : 0;
    int s = v;
    #pragma unroll
    for (int off = 1; off < 64; off <<= 1) {
        const int t = __shfl_up(s, off, 64);
        if ((tid & 63) >= off) s += t;
    }
    const int wave = tid >> 6;
    if ((tid & 63) == 63) u.s.wsum[wave] = s;
    __syncthreads();
    if (tid < 16) {
        const int ws = u.s.wsum[tid];
        int sc = ws;
        #pragma unroll
        for (int off = 1; off < 16; off <<= 1) {
            const int t = __shfl_up(sc, off, 64);
            if (tid >= off) sc += t;
        }
        u.s.woff[tid] = sc - ws;   // exclusive wave offset
    }
    __syncthreads();

    int* trow = toff + (size_t)blockIdx.x * (nb + 1);
    if (tid < nb) {
        const int start = s + u.s.woff[wave] - v;   // exclusive start
        u.s.lcur[tid] = start;
        trow[tid] = start;
    }
    if (tid == 0) trow[nb] = cnt;
    __syncthreads();

    // Pass B: rank (LDS cursor) and write records DIRECTLY permuted into LDS.
    #pragma unroll
    for (int it = 0; it < 2; ++it) {
        const int t = tid + it * BSTH;
        if (t < cnt4) {
            int b, r;
            b = rd[it].x >> NPB_SHIFT; r = atomicAdd(&u.s.lcur[b], 1);
            u.s.ebuf2[r] = make_int2(rs[it].x | ((rd[it].x & (NPB - 1)) << 20), __float_as_int(rv[it].x));
            b = rd[it].y >> NPB_SHIFT; r = atomicAdd(&u.s.lcur[b], 1);
            u.s.ebuf2[r] = make_int2(rs[it].y | ((rd[it].y & (NPB - 1)) << 20), __float_as_int(rv[it].y));
            b = rd[it].z >> NPB_SHIFT; r = atomicAdd(&u.s.lcur[b], 1);
            u.s.ebuf2[r] = make_int2(rs[it].z | ((rd[it].z & (NPB - 1)) << 20), __float_as_int(rv[it].z));
            b = rd[it].w >> NPB_SHIFT; r = atomicAdd(&u.s.lcur[b], 1);
            u.s.ebuf2[r] = make_int2(rs[it].w | ((rd[it].w & (NPB - 1)) << 20), __float_as_int(rv[it].w));
        }
    }
    if (tid == 0) {   // tail
        for (int e = cnt4 << 2; e < cnt; ++e) {
            const int dd = edge_dst[te + e];
            const int b = dd >> NPB_SHIFT;
            const int r = atomicAdd(&u.s.lcur[b], 1);
            u.s.ebuf2[r] = make_int2(edge_src[te + e] | ((dd & (NPB - 1)) << 20),
                                     __float_as_int(edge_val[te + e]));
        }
    }
    __syncthreads();

    // Pass C: stream the sorted tile to its private region (coalesced).
    for (int k = tid; k < cnt; k += BSTH)
        sorted[(size_t)te + k] = u.s.ebuf2[k];
}

// ---------------------------------------------------------------------------
// baccum v5 (round-12 verbatim — measured best: VGPR 40, ~33% occ, ~43 us):
// LDS ebuf staging, 8 lanes/edge uint4 gather, register acc, fused ReLU.
// (v6's register staging raised VGPR to 68 -> occupancy 16% -> 67 us. Do not
//  re-trade the ebuf pass for registers.)
// ---------------------------------------------------------------------------
__global__ __launch_bounds__(512) void baccum_kernel(const unsigned short* __restrict__ support,
                                                     const int2* __restrict__ sorted,
                                                     const int* __restrict__ toff,
                                                     float* __restrict__ out,
                                                     int n_nodes, int T, int nb) {
    __shared__ int2 ebuf[ECAP];
    __shared__ int2 ebuf2[ECAP];
    __shared__ int tstart[TMAX];
    __shared__ int toffb[TMAX];
    __shared__ int wsum3[4];
    __shared__ int total_s;
    __shared__ int hist[NPB];
    __shared__ int node_off[NPB + 1];
    __shared__ int cursor[NPB];
    __shared__ int wsum2[2];

    const int tid = threadIdx.x;
    const int b = blockIdx.x;

    int mycnt = 0, myoff = 0;
    if (tid < TMAX) {
        if (tid < T) {
            const int s0 = toff[(size_t)tid * (nb + 1) + b];
            const int e0 = toff[(size_t)tid * (nb + 1) + b + 1];
            toffb[tid] = s0;
            mycnt = e0 - s0;
        }
        int s = mycnt;
        #pragma unroll
        for (int off = 1; off < 64; off <<= 1) {
            const int t = __shfl_up(s, off, 64);
            if ((tid & 63) >= off) s += t;
        }
        if ((tid & 63) == 63) wsum3[tid >> 6] = s;
        myoff = s - mycnt;
    }
    __syncthreads();
    if (tid < TMAX && tid < T) {
        int add = 0;
        const int wv = tid >> 6;
        for (int q2 = 0; q2 < wv; ++q2) add += wsum3[q2];
        tstart[tid] = myoff + add;
    }
    if (tid == 0) total_s = wsum3[0] + wsum3[1] + wsum3[2] + wsum3[3];
    __syncthreads();
    const int total = total_s;

    const int g8 = tid >> 3;        // group 0..63 (owns nodes g8, g8+64)
    const int q  = tid & 7;         // uint4 slot: feats 8q..8q+7
    const uint4* sup = (const uint4*)support;   // row = 8 uint4 = 128 B

    float4 accA[2], accB[2];        // node j: feats 8q..8q+3 / 8q+4..8q+7
    #pragma unroll
    for (int j = 0; j < 2; ++j) {
        accA[j] = make_float4(0.f, 0.f, 0.f, 0.f);
        accB[j] = make_float4(0.f, 0.f, 0.f, 0.f);
    }

    for (int cb = 0; cb < total; cb += ECAP) {
        const int cnt = min(ECAP, total - cb);

        __syncthreads();
        if (tid < NPB) hist[tid] = 0;
        __syncthreads();

        // Stage + histogram (tile via binary search over tstart).
        for (int i = tid; i < cnt; i += 512) {
            const int g = cb + i;
            int lo = 0, hi = T - 1;
            while (lo < hi) {
                const int mid = (lo + hi + 1) >> 1;
                if (tstart[mid] <= g) lo = mid; else hi = mid - 1;
            }
            const int2 ev = sorted[(size_t)lo * TILE + toffb[lo] + (g - tstart[lo])];
            ebuf[i] = ev;
            atomicAdd(&hist[((unsigned)ev.x) >> 20], 1);
        }
        __syncthreads();

        // Shuffle scan of 128 node bins (2 waves).
        {
            int v = 0;
            if (tid < NPB) v = hist[tid];
            int s = v;
            if (tid < NPB) {
                #pragma unroll
                for (int off = 1; off < 64; off <<= 1) {
                    const int t = __shfl_up(s, off, 64);
                    if ((tid & 63) >= off) s += t;
                }
                if ((tid & 63) == 63) wsum2[tid >> 6] = s;
            }
            __syncthreads();
            if (tid < NPB) {
                const int incl = s + ((tid >= 64) ? wsum2[0] : 0);
                node_off[tid + 1] = incl;
                cursor[tid] = incl - v;
                if (tid == 0) node_off[0] = 0;
            }
        }
        __syncthreads();

        // Permute into dstLocal-grouped ebuf2 (LDS only).
        for (int i = tid; i < cnt; i += 512) {
            const int2 ev = ebuf[i];
            const int r = atomicAdd(&cursor[((unsigned)ev.x) >> 20], 1);
            ebuf2[r] = ev;
        }
        __syncthreads();

        // Register gather, 8-wide independent uint4 batches.
        #pragma unroll
        for (int j = 0; j < 2; ++j) {
            const int nl = g8 + 64 * j;
            int k = node_off[nl];
            const int ke = node_off[nl + 1];
            float4 aA = accA[j], aB = accB[j];
            while (k + 8 <= ke) {
                int2 e[8];
                uint4 s[8];
                #pragma unroll
                for (int u2 = 0; u2 < 8; ++u2) e[u2] = ebuf2[k + u2];      // broadcast
                #pragma unroll
                for (int u2 = 0; u2 < 8; ++u2)
                    s[u2] = sup[(size_t)(e[u2].x & 0xFFFFF) * 8 + q];      // independent
                #pragma unroll
                for (int u2 = 0; u2 < 8; ++u2) {
                    const float v = __int_as_float(e[u2].y);
                    aA.x += v * __uint_as_float(s[u2].x << 16);
                    aA.y += v * __uint_as_float(s[u2].x & 0xFFFF0000u);
                    aA.z += v * __uint_as_float(s[u2].y << 16);
                    aA.w += v * __uint_as_float(s[u2].y & 0xFFFF0000u);
                    aB.x += v * __uint_as_float(s[u2].z << 16);
                    aB.y += v * __uint_as_float(s[u2].z & 0xFFFF0000u);
                    aB.z += v * __uint_as_float(s[u2].w << 16);
                    aB.w += v * __uint_as_float(s[u2].w & 0xFFFF0000u);
                }
                k += 8;
            }
            for (; k < ke; ++k) {
                const int2 e0 = ebuf2[k];
                const uint4 s0 = sup[(size_t)(e0.x & 0xFFFFF) * 8 + q];
                const float v0 = __int_as_float(e0.y);
                aA.x += v0 * __uint_as_float(s0.x << 16);
                aA.y += v0 * __uint_as_float(s0.x & 0xFFFF0000u);
                aA.z += v0 * __uint_as_float(s0.y << 16);
                aA.w += v0 * __uint_as_float(s0.y & 0xFFFF0000u);
                aB.x += v0 * __uint_as_float(s0.z << 16);
                aB.y += v0 * __uint_as_float(s0.z & 0xFFFF0000u);
                aB.z += v0 * __uint_as_float(s0.w << 16);
                aB.w += v0 * __uint_as_float(s0.w & 0xFFFF0000u);
            }
            accA[j] = aA; accB[j] = aB;
        }
    }

    // Writeout (empty buckets write zeros; ReLU(0)=0 matches segment_sum).
    const int base = b << NPB_SHIFT;
    #pragma unroll
    for (int j = 0; j < 2; ++j) {
        const int node = base + g8 + 64 * j;
        if (node < n_nodes) {
            float4 vA = accA[j], vB = accB[j];
            vA.x = fmaxf(vA.x, 0.f); vA.y = fmaxf(vA.y, 0.f);
            vA.z = fmaxf(vA.z, 0.f); vA.w = fmaxf(vA.w, 0.f);
            vB.x = fmaxf(vB.x, 0.f); vB.y = fmaxf(vB.y, 0.f);
            vB.z = fmaxf(vB.z, 0.f); vB.w = fmaxf(vB.w, 0.f);
            ((float4*)out)[(size_t)node * 16 + 2 * q + 0] = vA;
            ((float4*)out)[(size_t)node * 16 + 2 * q + 1] = vB;
        }
    }
}

// ---------------------------------------------------------------------------
// Fallback: atomic path with bf16 support.
// ---------------------------------------------------------------------------
__global__ __launch_bounds__(256) void scatter_kernel(const unsigned short* __restrict__ support,
                                                      const float* __restrict__ edge_val,
                                                      const int* __restrict__ edge_src,
                                                      const int* __restrict__ edge_dst,
                                                      float* __restrict__ out,
                                                      int n_edges) {
    const long gid = (long)blockIdx.x * blockDim.x + threadIdx.x;
    const int e = (int)(gid >> 4);
    if (e >= n_edges) return;
    const int q = (int)(gid & 15);
    const int src   = edge_src[e];
    const int dst   = edge_dst[e];
    const float val = edge_val[e];
    const uint2 s = ((const uint2*)support)[(size_t)src * 16 + q];
    float* o = &out[(size_t)dst * F_OUT + q * 4];
    atomicAdd(o + 0, val * __uint_as_float(s.x << 16));
    atomicAdd(o + 1, val * __uint_as_float(s.x & 0xFFFF0000u));
    atomicAdd(o + 2, val * __uint_as_float(s.y << 16));
    atomicAdd(o + 3, val * __uint_as_float(s.y & 0xFFFF0000u));
}

__global__ __launch_bounds__(256) void relu_kernel(float* __restrict__ out, int n4) {
    const int i = blockIdx.x * blockDim.x + threadIdx.x;
    if (i < n4) {
        float4 v = ((float4*)out)[i];
        v.x = fmaxf(v.x, 0.f); v.y = fmaxf(v.y, 0.f);
        v.z = fmaxf(v.z, 0.f); v.w = fmaxf(v.w, 0.f);
        ((float4*)out)[i] = v;
    }
}

extern "C" void kernel_launch(void* const* d_in, const int* in_sizes, int n_in,
                              void* d_out, int out_size, void* d_ws, size_t ws_size,
                              hipStream_t stream) {
    const float* x        = (const float*)d_in[0];
    const float* w        = (const float*)d_in[1];
    const float* edge_val = (const float*)d_in[2];
    const int*   edge_src = (const int*)d_in[3];
    const int*   edge_dst = (const int*)d_in[4];
    float* out = (float*)d_out;

    const int n_nodes = in_sizes[0] / F_IN;   // 100000
    const int n_edges = in_sizes[2];          // 1600000
    const int nb = (n_nodes + NPB - 1) >> NPB_SHIFT;   // 782 buckets
    const int T  = (n_edges + TILE - 1) / TILE;        // 196 tiles
    const int G  = (n_nodes + GROWS - 1) / GROWS;      // 782 gemm blocks

    // Workspace: support bf16 (12.8 MB) | sorted (12.85 MB) | toff (0.61 MB)
    char* p = (char*)d_ws;
    unsigned short* support = (unsigned short*)p;
    p += (size_t)n_nodes * F_OUT * sizeof(unsigned short);
    p = (char*)(((size_t)p + 15) & ~(size_t)15);
    int2* sorted = (int2*)p;  p += (size_t)T * TILE * sizeof(int2);
    int*  toff   = (int*)p;   p += (size_t)T * (nb + 1) * sizeof(int);
    const size_t ws_needed = (size_t)(p - (char*)d_ws);

    const bool ok = (ws_size >= ws_needed) && (nb <= BCAP) && (n_nodes < (1 << 20))
                    && (T <= TMAX);
    if (ok) {
        fused_kernel<<<T + G, BSTH, 0, stream>>>(x, w, support, n_nodes,
                                                 edge_val, edge_src, edge_dst,
                                                 toff, sorted, n_edges, nb, T);
        baccum_kernel<<<nb, 512, 0, stream>>>(support, sorted, toff, out,
                                              n_nodes, T, nb);
    } else {
        // gemm only (T=0 -> all blocks take the gemm role)
        fused_kernel<<<G, BSTH, 0, stream>>>(x, w, support, n_nodes,
                                             edge_val, edge_src, edge_dst,
                                             nullptr, nullptr, n_edges, nb, 0);
        hipMemsetAsync(d_out, 0, (size_t)out_size * sizeof(float), stream);
        const long st = (long)n_edges * 16;
        scatter_kernel<<<(int)((st + 255) / 256), 256, 0, stream>>>(
            support, edge_val, edge_src, edge_dst, out, n_edges);
        const int n4o = out_size / 4;
        relu_kernel<<<(n4o + 255) / 256, 256, 0, stream>>>(out, n4o);
    }
}

// Round 15
// 167.216 us; speedup vs baseline: 1.1757x; 1.0557x over previous
//
#include <hip/hip_runtime.h>

#define F_IN 128
#define F_OUT 64
#define GROWS 128        // rows per gemm block (2 rows/thread at 1024 thr)
#define XBSTRIDE 136     // bf16 elems per x_lds row (272 B = 17x16B, aligned+padded)

#define NPB 128          // nodes per bucket
#define NPB_SHIFT 7
#define BCAP 800         // max buckets (nb = 782)
#define ECAP 2560        // edges staged per LDS chunk in baccum
#define TILE 8192        // edges per tile in multisplit
#define BSTH 1024        // fused-kernel threads
#define TMAX 256         // max tiles (T = ceil(E/TILE) = 196)

// fp32 -> bf16 round-to-nearest-even.
__device__ inline unsigned f2bf(float f) {
    const unsigned u = __float_as_uint(f);
    return (u + 0x7FFFu + ((u >> 16) & 1u)) >> 16;
}
__device__ inline float bf_lo(unsigned u) { return __uint_as_float(u << 16); }
__device__ inline float bf_hi(unsigned u) { return __uint_as_float(u & 0xFFFF0000u); }

// Shared-memory union: gemm role vs multisplit role (whole-block roles).
struct GemmSh {
    float4 w[F_IN * F_OUT / 4];              // 32 KB (fp32)
    unsigned short xt[GROWS * XBSTRIDE];     // 34.8 KB (bf16 x tile)
};                                           // = 66.8 KB
struct ScatSh {
    int2 ebuf2[TILE];                        // 64 KB (rank-permuted records)
    int  h[BCAP];                            // 3.2 KB
    int  lcur[BCAP];                         // 3.2 KB
    int  wsum[16];
    int  woff[16];
};                                           // = 70.6 KB
union FusedSh { GemmSh g; ScatSh s; };       // ~71 KB -> 2 blocks/CU

// ---------------------------------------------------------------------------
// Fused kernel: blocks [0,T) = tile-private edge multisplit; blocks [T,T+G) =
// support(bf16) = x @ weight. x tile staged as bf16 -> union 100->71 KB ->
// 2 blocks/CU (was 1): doubles the wave pool for latency hiding. x reads are
// uint4 (8 bf16 k's, 16B aligned); unpack = 16 VALU per 64 FMAs.
// ---------------------------------------------------------------------------
__global__ __launch_bounds__(BSTH) void fused_kernel(const float* __restrict__ x,
                                                     const float* __restrict__ w,
                                                     unsigned short* __restrict__ support,
                                                     int n_nodes,
                                                     const float* __restrict__ edge_val,
                                                     const int* __restrict__ edge_src,
                                                     const int* __restrict__ edge_dst,
                                                     int* __restrict__ toff,
                                                     int2* __restrict__ sorted,
                                                     int n_edges, int nb, int T) {
    __shared__ FusedSh u;
    const int tid = threadIdx.x;

    if ((int)blockIdx.x >= T) {
        // ================= gemm role =================
        const int row0 = (blockIdx.x - T) * GROWS;

        {   // stage weight: 2048 f4, 2 per thread
            const float4* w4 = (const float4*)w;
            #pragma unroll
            for (int i = tid; i < F_IN * F_OUT / 4; i += BSTH) u.g.w[i] = w4[i];
        }
        {   // stage x tile as bf16: 128 rows x 16 chunks of 8 k's, 2/thread
            const float4* x4 = (const float4*)x;
            #pragma unroll
            for (int i = tid; i < GROWS * (F_IN / 8); i += BSTH) {
                const int r  = i >> 4;       // row 0..127
                const int k8 = i & 15;       // 8-k chunk 0..15
                const int row = row0 + r;
                float4 a = make_float4(0.f, 0.f, 0.f, 0.f);
                float4 b = make_float4(0.f, 0.f, 0.f, 0.f);
                if (row < n_nodes) {
                    a = x4[(size_t)row * (F_IN / 4) + 2 * k8 + 0];
                    b = x4[(size_t)row * (F_IN / 4) + 2 * k8 + 1];
                }
                uint4 o;
                o.x = f2bf(a.x) | (f2bf(a.y) << 16);
                o.y = f2bf(a.z) | (f2bf(a.w) << 16);
                o.z = f2bf(b.x) | (f2bf(b.y) << 16);
                o.w = f2bf(b.z) | (f2bf(b.w) << 16);
                *(uint4*)&u.g.xt[r * XBSTRIDE + k8 * 8] = o;   // 16B aligned
            }
        }
        __syncthreads();

        const int tf = tid & 15;     // feats 4tf..4tf+3
        const int tr = tid >> 4;     // rows tr and tr+64

        float acc[2][4] = {};
        #pragma unroll 2
        for (int k8 = 0; k8 < F_IN / 8; ++k8) {
            const uint4 xa = *(const uint4*)&u.g.xt[tr * XBSTRIDE + k8 * 8];
            const uint4 xb = *(const uint4*)&u.g.xt[(tr + 64) * XBSTRIDE + k8 * 8];
            float xA[8], xB[8];
            xA[0] = bf_lo(xa.x); xA[1] = bf_hi(xa.x); xA[2] = bf_lo(xa.y); xA[3] = bf_hi(xa.y);
            xA[4] = bf_lo(xa.z); xA[5] = bf_hi(xa.z); xA[6] = bf_lo(xa.w); xA[7] = bf_hi(xa.w);
            xB[0] = bf_lo(xb.x); xB[1] = bf_hi(xb.x); xB[2] = bf_lo(xb.y); xB[3] = bf_hi(xb.y);
            xB[4] = bf_lo(xb.z); xB[5] = bf_hi(xb.z); xB[6] = bf_lo(xb.w); xB[7] = bf_hi(xb.w);
            #pragma unroll
            for (int j = 0; j < 8; ++j) {
                const float4 wv = u.g.w[(8 * k8 + j) * 16 + tf];
                acc[0][0] += xA[j] * wv.x; acc[0][1] += xA[j] * wv.y;
                acc[0][2] += xA[j] * wv.z; acc[0][3] += xA[j] * wv.w;
                acc[1][0] += xB[j] * wv.x; acc[1][1] += xB[j] * wv.y;
                acc[1][2] += xB[j] * wv.z; acc[1][3] += xB[j] * wv.w;
            }
        }
        #pragma unroll
        for (int i = 0; i < 2; ++i) {
            const int row = row0 + tr + 64 * i;
            if (row < n_nodes) {
                ushort4 o;
                o.x = (unsigned short)f2bf(acc[i][0]);
                o.y = (unsigned short)f2bf(acc[i][1]);
                o.z = (unsigned short)f2bf(acc[i][2]);
                o.w = (unsigned short)f2bf(acc[i][3]);
                *(ushort4*)&support[(size_t)row * F_OUT + 4 * tf] = o;
            }
        }
        return;
    }

    // ================= multisplit role =================
    const int te  = blockIdx.x * TILE;
    const int cnt = min(TILE, n_edges - te);

    for (int i = tid; i < BCAP; i += BSTH) u.s.h[i] = 0;
    __syncthreads();

    // Pass A: load edges into REGISTERS (2 int4-tiles/thread) + LDS hist.
    const int cnt4 = cnt >> 2;
    const int4*   s4 = (const int4*)(edge_src + te);
    const int4*   d4 = (const int4*)(edge_dst + te);
    const float4* v4 = (const float4*)(edge_val + te);
    int4 rs[2], rd[2]; float4 rv[2];
    #pragma unroll
    for (int it = 0; it < 2; ++it) {
        const int t = tid + it * BSTH;
        if (t < cnt4) {
            rs[it] = s4[t]; rd[it] = d4[t]; rv[it] = v4[t];
            atomicAdd(&u.s.h[rd[it].x >> NPB_SHIFT], 1);
            atomicAdd(&u.s.h[rd[it].y >> NPB_SHIFT], 1);
            atomicAdd(&u.s.h[rd[it].z >> NPB_SHIFT], 1);
            atomicAdd(&u.s.h[rd[it].w >> NPB_SHIFT], 1);
        }
    }
    if (tid == 0) {   // tail (<=3 edges): hist only, ranked in pass B
        for (int e = cnt4 << 2; e < cnt; ++e)
            atomicAdd(&u.s.h[edge_dst[te + e] >> NPB_SHIFT], 1);
    }
    __syncthreads();

    // Shuffle-based block scan of bucket counts (16 waves).
    const int v = (tid < nb) ? u.s.h[tid] : 0;
    int s = v;
    #pragma unroll
    for (int off = 1; off < 64; off <<= 1) {
        const int t = __shfl_up(s, off, 64);
        if ((tid & 63) >= off) s += t;
    }
    const int wave = tid >> 6;
    if ((tid & 63) == 63) u.s.wsum[wave] = s;
    __syncthreads();
    if (tid < 16) {
        const int ws = u.s.wsum[tid];
        int sc = ws;
        #pragma unroll
        for (int off = 1; off < 16; off <<= 1) {
            const int t = __shfl_up(sc, off, 64);
            if (tid >= off) sc += t;
        }
        u.s.woff[tid] = sc - ws;   // exclusive wave offset
    }
    __syncthreads();

    int* trow = toff + (size_t)blockIdx.x * (nb + 1);
    if (tid < nb) {
        const int start = s + u.s.woff[wave] - v;   // exclusive start
        u.s.lcur[tid] = start;
        trow[tid] = start;
    }
    if (tid == 0) trow[nb] = cnt;
    __syncthreads();

    // Pass B: rank (LDS cursor) and write records DIRECTLY permuted into LDS.
    #pragma unroll
    for (int it = 0; it < 2; ++it) {
        const int t = tid + it * BSTH;
        if (t < cnt4) {
            int b, r;
            b = rd[it].x >> NPB_SHIFT; r = atomicAdd(&u.s.lcur[b], 1);
            u.s.ebuf2[r] = make_int2(rs[it].x | ((rd[it].x & (NPB - 1)) << 20), __float_as_int(rv[it].x));
            b = rd[it].y >> NPB_SHIFT; r = atomicAdd(&u.s.lcur[b], 1);
            u.s.ebuf2[r] = make_int2(rs[it].y | ((rd[it].y & (NPB - 1)) << 20), __float_as_int(rv[it].y));
            b = rd[it].z >> NPB_SHIFT; r = atomicAdd(&u.s.lcur[b], 1);
            u.s.ebuf2[r] = make_int2(rs[it].z | ((rd[it].z & (NPB - 1)) << 20), __float_as_int(rv[it].z));
            b = rd[it].w >> NPB_SHIFT; r = atomicAdd(&u.s.lcur[b], 1);
            u.s.ebuf2[r] = make_int2(rs[it].w | ((rd[it].w & (NPB - 1)) << 20), __float_as_int(rv[it].w));
        }
    }
    if (tid == 0) {   // tail
        for (int e = cnt4 << 2; e < cnt; ++e) {
            const int dd = edge_dst[te + e];
            const int b = dd >> NPB_SHIFT;
            const int r = atomicAdd(&u.s.lcur[b], 1);
            u.s.ebuf2[r] = make_int2(edge_src[te + e] | ((dd & (NPB - 1)) << 20),
                                     __float_as_int(edge_val[te + e]));
        }
    }
    __syncthreads();

    // Pass C: stream the sorted tile to its private region (coalesced).
    for (int k = tid; k < cnt; k += BSTH)
        sorted[(size_t)te + k] = u.s.ebuf2[k];
}

// ---------------------------------------------------------------------------
// baccum v5 (measured best: VGPR 40, ~33% occ, ~43 us): LDS ebuf staging,
// 8 lanes/edge uint4 gather, register acc, fused ReLU.
// (v6's register staging raised VGPR to 68 -> occupancy 16% -> 67 us.)
// ---------------------------------------------------------------------------
__global__ __launch_bounds__(512) void baccum_kernel(const unsigned short* __restrict__ support,
                                                     const int2* __restrict__ sorted,
                                                     const int* __restrict__ toff,
                                                     float* __restrict__ out,
                                                     int n_nodes, int T, int nb) {
    __shared__ int2 ebuf[ECAP];
    __shared__ int2 ebuf2[ECAP];
    __shared__ int tstart[TMAX];
    __shared__ int toffb[TMAX];
    __shared__ int wsum3[4];
    __shared__ int total_s;
    __shared__ int hist[NPB];
    __shared__ int node_off[NPB + 1];
    __shared__ int cursor[NPB];
    __shared__ int wsum2[2];

    const int tid = threadIdx.x;
    const int b = blockIdx.x;

    int mycnt = 0, myoff = 0;
    if (tid < TMAX) {
        if (tid < T) {
            const int s0 = toff[(size_t)tid * (nb + 1) + b];
            const int e0 = toff[(size_t)tid * (nb + 1) + b + 1];
            toffb[tid] = s0;
            mycnt = e0 - s0;
        }
        int s = mycnt;
        #pragma unroll
        for (int off = 1; off < 64; off <<= 1) {
            const int t = __shfl_up(s, off, 64);
            if ((tid & 63) >= off) s += t;
        }
        if ((tid & 63) == 63) wsum3[tid >> 6] = s;
        myoff = s - mycnt;
    }
    __syncthreads();
    if (tid < TMAX && tid < T) {
        int add = 0;
        const int wv = tid >> 6;
        for (int q2 = 0; q2 < wv; ++q2) add += wsum3[q2];
        tstart[tid] = myoff + add;
    }
    if (tid == 0) total_s = wsum3[0] + wsum3[1] + wsum3[2] + wsum3[3];
    __syncthreads();
    const int total = total_s;

    const int g8 = tid >> 3;        // group 0..63 (owns nodes g8, g8+64)
    const int q  = tid & 7;         // uint4 slot: feats 8q..8q+7
    const uint4* sup = (const uint4*)support;   // row = 8 uint4 = 128 B

    float4 accA[2], accB[2];        // node j: feats 8q..8q+3 / 8q+4..8q+7
    #pragma unroll
    for (int j = 0; j < 2; ++j) {
        accA[j] = make_float4(0.f, 0.f, 0.f, 0.f);
        accB[j] = make_float4(0.f, 0.f, 0.f, 0.f);
    }

    for (int cb = 0; cb < total; cb += ECAP) {
        const int cnt = min(ECAP, total - cb);

        __syncthreads();
        if (tid < NPB) hist[tid] = 0;
        __syncthreads();

        // Stage + histogram (tile via binary search over tstart).
        for (int i = tid; i < cnt; i += 512) {
            const int g = cb + i;
            int lo = 0, hi = T - 1;
            while (lo < hi) {
                const int mid = (lo + hi + 1) >> 1;
                if (tstart[mid] <= g) lo = mid; else hi = mid - 1;
            }
            const int2 ev = sorted[(size_t)lo * TILE + toffb[lo] + (g - tstart[lo])];
            ebuf[i] = ev;
            atomicAdd(&hist[((unsigned)ev.x) >> 20], 1);
        }
        __syncthreads();

        // Shuffle scan of 128 node bins (2 waves).
        {
            int v = 0;
            if (tid < NPB) v = hist[tid];
            int s = v;
            if (tid < NPB) {
                #pragma unroll
                for (int off = 1; off < 64; off <<= 1) {
                    const int t = __shfl_up(s, off, 64);
                    if ((tid & 63) >= off) s += t;
                }
                if ((tid & 63) == 63) wsum2[tid >> 6] = s;
            }
            __syncthreads();
            if (tid < NPB) {
                const int incl = s + ((tid >= 64) ? wsum2[0] : 0);
                node_off[tid + 1] = incl;
                cursor[tid] = incl - v;
                if (tid == 0) node_off[0] = 0;
            }
        }
        __syncthreads();

        // Permute into dstLocal-grouped ebuf2 (LDS only).
        for (int i = tid; i < cnt; i += 512) {
            const int2 ev = ebuf[i];
            const int r = atomicAdd(&cursor[((unsigned)ev.x) >> 20], 1);
            ebuf2[r] = ev;
        }
        __syncthreads();

        // Register gather, 8-wide independent uint4 batches.
        #pragma unroll
        for (int j = 0; j < 2; ++j) {
            const int nl = g8 + 64 * j;
            int k = node_off[nl];
            const int ke = node_off[nl + 1];
            float4 aA = accA[j], aB = accB[j];
            while (k + 8 <= ke) {
                int2 e[8];
                uint4 s[8];
                #pragma unroll
                for (int u2 = 0; u2 < 8; ++u2) e[u2] = ebuf2[k + u2];      // broadcast
                #pragma unroll
                for (int u2 = 0; u2 < 8; ++u2)
                    s[u2] = sup[(size_t)(e[u2].x & 0xFFFFF) * 8 + q];      // independent
                #pragma unroll
                for (int u2 = 0; u2 < 8; ++u2) {
                    const float v = __int_as_float(e[u2].y);
                    aA.x += v * bf_lo(s[u2].x); aA.y += v * bf_hi(s[u2].x);
                    aA.z += v * bf_lo(s[u2].y); aA.w += v * bf_hi(s[u2].y);
                    aB.x += v * bf_lo(s[u2].z); aB.y += v * bf_hi(s[u2].z);
                    aB.z += v * bf_lo(s[u2].w); aB.w += v * bf_hi(s[u2].w);
                }
                k += 8;
            }
            for (; k < ke; ++k) {
                const int2 e0 = ebuf2[k];
                const uint4 s0 = sup[(size_t)(e0.x & 0xFFFFF) * 8 + q];
                const float v0 = __int_as_float(e0.y);
                aA.x += v0 * bf_lo(s0.x); aA.y += v0 * bf_hi(s0.x);
                aA.z += v0 * bf_lo(s0.y); aA.w += v0 * bf_hi(s0.y);
                aB.x += v0 * bf_lo(s0.z); aB.y += v0 * bf_hi(s0.z);
                aB.z += v0 * bf_lo(s0.w); aB.w += v0 * bf_hi(s0.w);
            }
            accA[j] = aA; accB[j] = aB;
        }
    }

    // Writeout (empty buckets write zeros; ReLU(0)=0 matches segment_sum).
    const int base = b << NPB_SHIFT;
    #pragma unroll
    for (int j = 0; j < 2; ++j) {
        const int node = base + g8 + 64 * j;
        if (node < n_nodes) {
            float4 vA = accA[j], vB = accB[j];
            vA.x = fmaxf(vA.x, 0.f); vA.y = fmaxf(vA.y, 0.f);
            vA.z = fmaxf(vA.z, 0.f); vA.w = fmaxf(vA.w, 0.f);
            vB.x = fmaxf(vB.x, 0.f); vB.y = fmaxf(vB.y, 0.f);
            vB.z = fmaxf(vB.z, 0.f); vB.w = fmaxf(vB.w, 0.f);
            ((float4*)out)[(size_t)node * 16 + 2 * q + 0] = vA;
            ((float4*)out)[(size_t)node * 16 + 2 * q + 1] = vB;
        }
    }
}

// ---------------------------------------------------------------------------
// Fallback: atomic path with bf16 support.
// ---------------------------------------------------------------------------
__global__ __launch_bounds__(256) void scatter_kernel(const unsigned short* __restrict__ support,
                                                      const float* __restrict__ edge_val,
                                                      const int* __restrict__ edge_src,
                                                      const int* __restrict__ edge_dst,
                                                      float* __restrict__ out,
                                                      int n_edges) {
    const long gid = (long)blockIdx.x * blockDim.x + threadIdx.x;
    const int e = (int)(gid >> 4);
    if (e >= n_edges) return;
    const int q = (int)(gid & 15);
    const int src   = edge_src[e];
    const int dst   = edge_dst[e];
    const float val = edge_val[e];
    const uint2 s = ((const uint2*)support)[(size_t)src * 16 + q];
    float* o = &out[(size_t)dst * F_OUT + q * 4];
    atomicAdd(o + 0, val * bf_lo(s.x));
    atomicAdd(o + 1, val * bf_hi(s.x));
    atomicAdd(o + 2, val * bf_lo(s.y));
    atomicAdd(o + 3, val * bf_hi(s.y));
}

__global__ __launch_bounds__(256) void relu_kernel(float* __restrict__ out, int n4) {
    const int i = blockIdx.x * blockDim.x + threadIdx.x;
    if (i < n4) {
        float4 v = ((float4*)out)[i];
        v.x = fmaxf(v.x, 0.f); v.y = fmaxf(v.y, 0.f);
        v.z = fmaxf(v.z, 0.f); v.w = fmaxf(v.w, 0.f);
        ((float4*)out)[i] = v;
    }
}

extern "C" void kernel_launch(void* const* d_in, const int* in_sizes, int n_in,
                              void* d_out, int out_size, void* d_ws, size_t ws_size,
                              hipStream_t stream) {
    const float* x        = (const float*)d_in[0];
    const float* w        = (const float*)d_in[1];
    const float* edge_val = (const float*)d_in[2];
    const int*   edge_src = (const int*)d_in[3];
    const int*   edge_dst = (const int*)d_in[4];
    float* out = (float*)d_out;

    const int n_nodes = in_sizes[0] / F_IN;   // 100000
    const int n_edges = in_sizes[2];          // 1600000
    const int nb = (n_nodes + NPB - 1) >> NPB_SHIFT;   // 782 buckets
    const int T  = (n_edges + TILE - 1) / TILE;        // 196 tiles
    const int G  = (n_nodes + GROWS - 1) / GROWS;      // 782 gemm blocks

    // Workspace: support bf16 (12.8 MB) | sorted (12.85 MB) | toff (0.61 MB)
    char* p = (char*)d_ws;
    unsigned short* support = (unsigned short*)p;
    p += (size_t)n_nodes * F_OUT * sizeof(unsigned short);
    p = (char*)(((size_t)p + 15) & ~(size_t)15);
    int2* sorted = (int2*)p;  p += (size_t)T * TILE * sizeof(int2);
    int*  toff   = (int*)p;   p += (size_t)T * (nb + 1) * sizeof(int);
    const size_t ws_needed = (size_t)(p - (char*)d_ws);

    const bool ok = (ws_size >= ws_needed) && (nb <= BCAP) && (n_nodes < (1 << 20))
                    && (T <= TMAX);
    if (ok) {
        fused_kernel<<<T + G, BSTH, 0, stream>>>(x, w, support, n_nodes,
                                                 edge_val, edge_src, edge_dst,
                                                 toff, sorted, n_edges, nb, T);
        baccum_kernel<<<nb, 512, 0, stream>>>(support, sorted, toff, out,
                                              n_nodes, T, nb);
    } else {
        // gemm only (T=0 -> all blocks take the gemm role)
        fused_kernel<<<G, BSTH, 0, stream>>>(x, w, support, n_nodes,
                                             edge_val, edge_src, edge_dst,
                                             nullptr, nullptr, n_edges, nb, 0);
        hipMemsetAsync(d_out, 0, (size_t)out_size * sizeof(float), stream);
        const long st = (long)n_edges * 16;
        scatter_kernel<<<(int)((st + 255) / 256), 256, 0, stream>>>(
            support, edge_val, edge_src, edge_dst, out, n_edges);
        const int n4o = out_size / 4;
        relu_kernel<<<(n4o + 255) / 256, 256, 0, stream>>>(out, n4o);
    }
}